// Round 10
// baseline (241.310 us; speedup 1.0000x reference)
//
#include <hip/hip_runtime.h>
#include <hip/hip_bf16.h>
#include <math.h>

#define NF 128

typedef short bf16x8 __attribute__((ext_vector_type(8)));
typedef float f32x4  __attribute__((ext_vector_type(4)));

union U8 { unsigned u[4]; bf16x8 v; };

__device__ __forceinline__ unsigned pk2(float lo, float hi) {
    union { __hip_bfloat162 h2; unsigned u; } c;
    c.h2 = __float22bfloat162_rn(make_float2(lo, hi));
    return c.u;    // low 16 bits = lo
}
__device__ __forceinline__ unsigned short f2bf(float f) {
    union { __hip_bfloat16 h; unsigned short u; } c;
    c.h = __float2bfloat16(f);
    return c.u;
}

// ---------------- K_prep: segtab + node segloc + W transpose ----------------
__global__ void k_prep(const int* __restrict__ ptr, const int* __restrict__ split,
                       int nB, int N, int nseg,
                       unsigned* __restrict__ segloc, int* __restrict__ segstart,
                       int* __restrict__ segcnt,
                       const float* __restrict__ W1, const float* __restrict__ W2,
                       short* __restrict__ Wt1, short* __restrict__ Wt2) {
    int i = blockIdx.x * blockDim.x + threadIdx.x;
    if (i < N) {
        int lo = 0, hi = nB + 1;
        while (lo < hi) { int mid = (lo + hi) >> 1; if (ptr[mid] <= i) lo = mid + 1; else hi = mid; }
        int g = lo - 1;
        int local = i - ptr[g];
        int sp = split[g];
        int drug = (local >= sp) ? 1 : 0;
        int seg = 2 * g + drug;
        int loc = local - (drug ? sp : 0);
        segloc[i] = ((unsigned)seg << 8) | (unsigned)loc;
    }
    if (i < nseg) {
        int g = i >> 1;
        int base = ptr[g];
        int sp = split[g];
        segstart[i] = (i & 1) ? base + sp : base;
        segcnt[i]   = (i & 1) ? (ptr[g + 1] - base - sp) : sp;
    }
    if (i < 32768) {
        int m = i >> 14;            // 0 -> W1, 1 -> W2
        int rem = i & 16383;
        int n = rem & 127;          // consecutive lanes -> coalesced read
        int k = rem >> 7;
        const float* W = m ? W2 : W1;
        short* Wt = m ? Wt2 : Wt1;
        Wt[n * 128 + k] = (short)f2bf(W[k * 128 + n]);
    }
}

// ---------------- K_cnt: nibble-packed adjacency histogram ----------------
// Abits[seg*128 + (d*32+s)/8] accumulates 4-bit counts (dup edges < 16, Poisson(0.25)).
__global__ void k_cnt(const int* __restrict__ src, const int* __restrict__ dst, int E,
                      const unsigned* __restrict__ segloc, unsigned* __restrict__ Abits) {
    int e = blockIdx.x * blockDim.x + threadIdx.x;
    if (e >= E) return;
    unsigned ss = segloc[src[e]], dd = segloc[dst[e]];
    if ((ss >> 8) == (dd >> 8) && ((ss | dd) & 0xE0u) == 0u) {
        unsigned eidx = (dd & 31u) * 32u + (ss & 31u);   // dst-row-major entry
        atomicAdd(&Abits[(ss >> 8) * 128u + (eidx >> 3)], 1u << (4u * (eidx & 7u)));
    }
}

// ---------------- K_gcn6: fused A-extract + 2-layer GCN + pool ----------------
// One segment per block, 2 waves (128 thr). Wave w owns feat/fout half 64w..64w+63.
// Single 10.25 KB LDS buffer role-switched: xt (feat-major [128][40]) <-> zb ([32][128] XOR-swz).
__global__ void __launch_bounds__(128, 6) k_gcn6(
    const float* __restrict__ x,
    const int* __restrict__ segstart, const int* __restrict__ segcnt,
    const unsigned* __restrict__ Abits,
    const short* __restrict__ Wt1, const float* __restrict__ b1,
    const short* __restrict__ Wt2, const float* __restrict__ b2,
    float* __restrict__ pooled)
{
    __shared__ short xt[128 * 40];
    __shared__ float dv[32];
    short* zb = xt;

    const int seg = blockIdx.x;
    const int t  = threadIdx.x;
    const int wv = t >> 6;
    const int l  = t & 63;
    const int fr = l & 15;
    const int g  = l >> 4;
    const int swz = (fr & 7) << 3;

    const int start = segstart[seg];
    const int cnt   = segcnt[seg];

    // ---- 1. issue X loads into registers (HBM latency hides under A-extract)
    const int f0 = (t & 15) * 8;       // 8 feats
    const int c0 = (t >> 4) * 4;       // 4 cols
    float xr[4][8];
    #pragma unroll
    for (int i = 0; i < 4; ++i) {
        if (c0 + i < cnt) {
            const float4* rp = (const float4*)(x + (size_t)(start + c0 + i) * NF + f0);
            float4 a = rp[0], b = rp[1];
            xr[i][0]=a.x; xr[i][1]=a.y; xr[i][2]=a.z; xr[i][3]=a.w;
            xr[i][4]=b.x; xr[i][5]=b.y; xr[i][6]=b.z; xr[i][7]=b.w;
        } else {
            #pragma unroll
            for (int j = 0; j < 8; ++j) xr[i][j] = 0.f;
        }
    }

    // ---- 2. A counts from nibble bitmap: lane covers rows fr & 16+fr, cols g*8..g*8+7
    const unsigned* ab = Abits + (size_t)seg * 128;
    const unsigned wd0 = ab[fr * 4 + g];
    const unsigned wd1 = ab[(16 + fr) * 4 + g];

    int s0 = 0, s1 = 0;
    #pragma unroll
    for (int j = 0; j < 8; ++j) {
        s0 += (int)((wd0 >> (4 * j)) & 15u);
        s1 += (int)((wd1 >> (4 * j)) & 15u);
    }
    s0 += __shfl_xor(s0, 16); s0 += __shfl_xor(s0, 32);   // row sums over col groups
    s1 += __shfl_xor(s1, 16); s1 += __shfl_xor(s1, 32);
    float dv0 = rsqrtf(1.0f + (float)s0);
    float dv1 = rsqrtf(1.0f + (float)s1);
    if (t < 16) { dv[t] = dv0; dv[16 + t] = dv1; }

    // ---- 3. store X transposed into xt (bf16 feat-major, stride 40)
    #pragma unroll
    for (int j = 0; j < 8; ++j) {
        uint2 w;
        w.x = pk2(xr[0][j], xr[1][j]);
        w.y = pk2(xr[2][j], xr[3][j]);
        *reinterpret_cast<uint2*>(&xt[(f0 + j) * 40 + c0]) = w;
    }
    __syncthreads();

    // ---- 4. finalize A into register B-fragments (rows fr, 16+fr; cols g*8..+7)
    bf16x8 bfr0, bfr1;
    {
        float dr0 = dv[fr];
        float dr1 = dv[16 + fr];
        float e0[8], e1[8];
        #pragma unroll
        for (int j = 0; j < 8; ++j) {
            int c = g * 8 + j;
            float dc = dv[c];
            float v0 = (float)((wd0 >> (4 * j)) & 15u) * dr0 * dc;
            float v1 = (float)((wd1 >> (4 * j)) & 15u) * dr1 * dc;
            if (c == fr)      v0 += dr0 * dr0;
            if (c == 16 + fr) v1 += dr1 * dr1;
            e0[j] = v0; e1[j] = v1;
        }
        U8 u0, u1;
        u0.u[0] = pk2(e0[0], e0[1]); u0.u[1] = pk2(e0[2], e0[3]);
        u0.u[2] = pk2(e0[4], e0[5]); u0.u[3] = pk2(e0[6], e0[7]);
        u1.u[0] = pk2(e1[0], e1[1]); u1.u[1] = pk2(e1[2], e1[3]);
        u1.u[2] = pk2(e1[4], e1[5]); u1.u[3] = pk2(e1[6], e1[7]);
        bfr0 = u0.v; bfr1 = u1.v;
    }

    // ---- 5. two GCN layers (wave w owns feat half 64w..64w+63)
    for (int layer = 0; layer < 2; ++layer) {
        const short* Wt = layer ? Wt2 : Wt1;
        const float* bb = layer ? b2  : b1;

        // Z-phase: wave w computes mt = 4w..4w+3 into registers
        unsigned zp[4][4];
        __builtin_amdgcn_s_setprio(1);
        #pragma unroll
        for (int mi = 0; mi < 4; ++mi) {
            int mt = wv * 4 + mi;
            bf16x8 af = *(const bf16x8*)&xt[(mt * 16 + fr) * 40 + g * 8];
            f32x4 z0 = {0.f, 0.f, 0.f, 0.f};
            f32x4 z1 = {0.f, 0.f, 0.f, 0.f};
            z0 = __builtin_amdgcn_mfma_f32_16x16x32_bf16(af, bfr0, z0, 0, 0, 0);
            z1 = __builtin_amdgcn_mfma_f32_16x16x32_bf16(af, bfr1, z1, 0, 0, 0);
            zp[mi][0] = pk2(z0[0], z0[1]); zp[mi][1] = pk2(z0[2], z0[3]);
            zp[mi][2] = pk2(z1[0], z1[1]); zp[mi][3] = pk2(z1[2], z1[3]);
        }
        __builtin_amdgcn_s_setprio(0);
        __syncthreads();    // all xt reads retired; buffer becomes zb

        #pragma unroll
        for (int mi = 0; mi < 4; ++mi) {
            int fb = (wv * 4 + mi) * 16 + 4 * g;
            uint2 w0, w1;
            w0.x = zp[mi][0]; w0.y = zp[mi][1];
            w1.x = zp[mi][2]; w1.y = zp[mi][3];
            *reinterpret_cast<uint2*>(&zb[fr * 128 + (fb ^ swz)])        = w0;
            *reinterpret_cast<uint2*>(&zb[(16 + fr) * 128 + (fb ^ swz)]) = w1;
        }
        __syncthreads();

        // H-phase: wave w computes nt = 4w..4w+3 (fouts 64w..64w+63), K = all 128
        f32x4 acc[2][4];
        #pragma unroll
        for (int i = 0; i < 2; ++i)
            #pragma unroll
            for (int j = 0; j < 4; ++j) acc[i][j] = (f32x4){0.f, 0.f, 0.f, 0.f};
        #pragma unroll
        for (int kk = 0; kk < 4; ++kk) {
            const int ko = kk * 32 + g * 8;
            bf16x8 a0 = *(const bf16x8*)&zb[fr * 128 + (ko ^ swz)];
            bf16x8 a1 = *(const bf16x8*)&zb[(16 + fr) * 128 + (ko ^ swz)];
            __builtin_amdgcn_s_setprio(1);
            #pragma unroll
            for (int ni = 0; ni < 4; ++ni) {
                int nt = wv * 4 + ni;
                bf16x8 wf = *(const bf16x8*)&Wt[(nt * 16 + fr) * 128 + ko];
                acc[0][ni] = __builtin_amdgcn_mfma_f32_16x16x32_bf16(a0, wf, acc[0][ni], 0, 0, 0);
                acc[1][ni] = __builtin_amdgcn_mfma_f32_16x16x32_bf16(a1, wf, acc[1][ni], 0, 0, 0);
            }
            __builtin_amdgcn_s_setprio(0);
        }
        __syncthreads();    // zb reads retired (both waves)

        if (layer == 0) {
            #pragma unroll
            for (int ni = 0; ni < 4; ++ni) {
                int nt = wv * 4 + ni;
                float bv = bb[nt * 16 + fr];
                #pragma unroll
                for (int mt = 0; mt < 2; ++mt) {
                    float h0 = acc[mt][ni][0] + bv; h0 = h0 > 0.f ? h0 : 0.f;
                    float h1 = acc[mt][ni][1] + bv; h1 = h1 > 0.f ? h1 : 0.f;
                    float h2 = acc[mt][ni][2] + bv; h2 = h2 > 0.f ? h2 : 0.f;
                    float h3 = acc[mt][ni][3] + bv; h3 = h3 > 0.f ? h3 : 0.f;
                    uint2 w;
                    w.x = pk2(h0, h1); w.y = pk2(h2, h3);
                    *reinterpret_cast<uint2*>(&xt[(nt * 16 + fr) * 40 + mt * 16 + 4 * g]) = w;
                }
            }
            __syncthreads();
        } else {
            // mean pool in registers + shfl; wave w writes fouts 64w..64w+63
            float rcpc = 1.0f / (float)(cnt > 0 ? cnt : 1);
            #pragma unroll
            for (int ni = 0; ni < 4; ++ni) {
                int nt = wv * 4 + ni;
                float bv = bb[nt * 16 + fr];
                float pm = 0.f;
                #pragma unroll
                for (int mt = 0; mt < 2; ++mt)
                    #pragma unroll
                    for (int r = 0; r < 4; ++r) {
                        int node = mt * 16 + 4 * g + r;
                        float h = acc[mt][ni][r] + bv;
                        h = h > 0.f ? h : 0.f;
                        if (node < cnt) pm += h;
                    }
                pm += __shfl_xor(pm, 16);
                pm += __shfl_xor(pm, 32);
                if (l < 16) pooled[(size_t)seg * NF + nt * 16 + l] = pm * rcpc;
            }
        }
    }
}

// ---------------- K_mlp: pair MLP + sigmoid, 4 pairs per block ----------------
__global__ void __launch_bounds__(128) k_mlp(
    const float* __restrict__ pooled, const float* __restrict__ Wm1,
    const float* __restrict__ bm1, const float* __restrict__ Wm2,
    const float* __restrict__ bm2, float* __restrict__ out, int nB) {
    __shared__ float pr[4][256];
    __shared__ float red[4][2];
    const int b0 = blockIdx.x * 4;
    const int t = threadIdx.x;

    for (int i = t; i < 1024; i += 128) {
        int p = i >> 8, c = i & 255;
        int pair = b0 + p;
        pr[p][c] = (pair < nB) ? pooled[(size_t)(2 * pair + (c >> 7)) * 128 + (c & 127)] : 0.f;
    }
    __syncthreads();

    float acc0 = bm1[t], acc1 = acc0, acc2 = acc0, acc3 = acc0;
    #pragma unroll 4
    for (int k = 0; k < 256; ++k) {
        float w = Wm1[k * 128 + t];
        acc0 += pr[0][k] * w;
        acc1 += pr[1][k] * w;
        acc2 += pr[2][k] * w;
        acc3 += pr[3][k] * w;
    }
    float wm2 = Wm2[t];
    float v[4];
    v[0] = (acc0 > 0.f ? acc0 : 0.f) * wm2;
    v[1] = (acc1 > 0.f ? acc1 : 0.f) * wm2;
    v[2] = (acc2 > 0.f ? acc2 : 0.f) * wm2;
    v[3] = (acc3 > 0.f ? acc3 : 0.f) * wm2;
    #pragma unroll
    for (int p = 0; p < 4; ++p) {
        #pragma unroll
        for (int o = 32; o > 0; o >>= 1) v[p] += __shfl_xor(v[p], o);
    }
    if ((t & 63) == 0) {
        int w = t >> 6;
        red[0][w] = v[0]; red[1][w] = v[1]; red[2][w] = v[2]; red[3][w] = v[3];
    }
    __syncthreads();
    if (t < 4 && b0 + t < nB) {
        float z = red[t][0] + red[t][1] + bm2[0];
        out[b0 + t] = 1.f / (1.f + expf(-z));
    }
}

static inline size_t alup(size_t v) { return (v + 255) & ~(size_t)255; }

extern "C" void kernel_launch(void* const* d_in, const int* in_sizes, int n_in,
                              void* d_out, int out_size, void* d_ws, size_t ws_size,
                              hipStream_t stream) {
    const float* x     = (const float*)d_in[0];
    const int*   edge  = (const int*)d_in[1];
    const int*   ptr   = (const int*)d_in[2];
    const int*   split = (const int*)d_in[3];
    const float* W1  = (const float*)d_in[4];
    const float* b1  = (const float*)d_in[5];
    const float* W2  = (const float*)d_in[6];
    const float* b2  = (const float*)d_in[7];
    const float* Wm1 = (const float*)d_in[8];
    const float* bm1 = (const float*)d_in[9];
    const float* Wm2 = (const float*)d_in[10];
    const float* bm2 = (const float*)d_in[11];
    float* out = (float*)d_out;

    const int N    = in_sizes[0] / NF;
    const int E    = in_sizes[1] / 2;
    const int nB   = in_sizes[2] - 1;
    const int nseg = 2 * nB;

    char* ws = (char*)d_ws;
    size_t off = 0;
    unsigned* segloc   = (unsigned*)(ws + off);  off += alup((size_t)N * 4);
    int*      segstart = (int*)(ws + off);       off += alup((size_t)nseg * 4);
    int*      segcnt   = (int*)(ws + off);       off += alup((size_t)nseg * 4);
    unsigned* Abits    = (unsigned*)(ws + off);  size_t abb = (size_t)nseg * 128 * 4; off += alup(abb);
    float*    pooled   = (float*)(ws + off);     off += alup((size_t)nseg * NF * 4);
    short*    Wt1      = (short*)(ws + off);     off += alup(128 * 128 * 2);
    short*    Wt2      = (short*)(ws + off);     off += alup(128 * 128 * 2);

    const int* srcp = edge;
    const int* dstp = edge + E;

    int prepN = N > 32768 ? N : 32768;
    if (prepN < nseg) prepN = nseg;

    hipMemsetAsync(Abits, 0, abb, stream);
    k_prep<<<(prepN + 255) / 256, 256, 0, stream>>>(ptr, split, nB, N, nseg,
                                                    segloc, segstart, segcnt,
                                                    W1, W2, Wt1, Wt2);
    k_cnt<<<(E + 255) / 256, 256, 0, stream>>>(srcp, dstp, E, segloc, Abits);
    k_gcn6<<<nseg, 128, 0, stream>>>(x, segstart, segcnt, Abits,
                                     Wt1, b1, Wt2, b2, pooled);
    k_mlp<<<(nB + 3) / 4, 128, 0, stream>>>(pooled, Wm1, bm1, Wm2, bm2, out, nB);
}

// Round 11
// 214.324 us; speedup vs baseline: 1.1259x; 1.1259x over previous
//
#include <hip/hip_runtime.h>
#include <hip/hip_bf16.h>
#include <math.h>

#define NF 128

typedef short bf16x8 __attribute__((ext_vector_type(8)));
typedef float f32x4  __attribute__((ext_vector_type(4)));

union U8 { unsigned u[4]; bf16x8 v; };

__device__ __forceinline__ unsigned pk2(float lo, float hi) {
    union { __hip_bfloat162 h2; unsigned u; } c;
    c.h2 = __float22bfloat162_rn(make_float2(lo, hi));
    return c.u;    // low 16 bits = lo
}
__device__ __forceinline__ unsigned short f2bf(float f) {
    union { __hip_bfloat16 h; unsigned short u; } c;
    c.h = __float2bfloat16(f);
    return c.u;
}

// ---------------- K_prep: segtab + node segloc + W transpose ----------------
__global__ void k_prep(const int* __restrict__ ptr, const int* __restrict__ split,
                       int nB, int N, int nseg,
                       unsigned* __restrict__ segloc, int* __restrict__ segstart,
                       int* __restrict__ segcnt,
                       const float* __restrict__ W1, const float* __restrict__ W2,
                       short* __restrict__ Wt1, short* __restrict__ Wt2) {
    int i = blockIdx.x * blockDim.x + threadIdx.x;
    if (i < N) {
        int lo = 0, hi = nB + 1;
        while (lo < hi) { int mid = (lo + hi) >> 1; if (ptr[mid] <= i) lo = mid + 1; else hi = mid; }
        int g = lo - 1;
        int local = i - ptr[g];
        int sp = split[g];
        int drug = (local >= sp) ? 1 : 0;
        int seg = 2 * g + drug;
        int loc = local - (drug ? sp : 0);
        segloc[i] = ((unsigned)seg << 8) | (unsigned)loc;
    }
    if (i < nseg) {
        int g = i >> 1;
        int base = ptr[g];
        int sp = split[g];
        segstart[i] = (i & 1) ? base + sp : base;
        segcnt[i]   = (i & 1) ? (ptr[g + 1] - base - sp) : sp;
    }
    if (i < 32768) {
        int m = i >> 14;            // 0 -> W1, 1 -> W2
        int rem = i & 16383;
        int n = rem & 127;          // consecutive lanes -> coalesced read
        int k = rem >> 7;
        const float* W = m ? W2 : W1;
        short* Wt = m ? Wt2 : Wt1;
        Wt[n * 128 + k] = (short)f2bf(W[k * 128 + n]);
    }
}

// ---------------- K_cnt: nibble-packed adjacency histogram ----------------
// Abits[seg*128 + (d*32+s)/8] accumulates 4-bit counts (dup edges < 16, Poisson(0.25)).
__global__ void k_cnt(const int* __restrict__ src, const int* __restrict__ dst, int E,
                      const unsigned* __restrict__ segloc, unsigned* __restrict__ Abits) {
    int e = blockIdx.x * blockDim.x + threadIdx.x;
    if (e >= E) return;
    unsigned ss = segloc[src[e]], dd = segloc[dst[e]];
    if ((ss >> 8) == (dd >> 8) && ((ss | dd) & 0xE0u) == 0u) {
        unsigned eidx = (dd & 31u) * 32u + (ss & 31u);   // dst-row-major entry
        atomicAdd(&Abits[(ss >> 8) * 128u + (eidx >> 3)], 1u << (4u * (eidx & 7u)));
    }
}

// ---------------- K_gcn6: fused A-extract + 2-layer GCN + pool ----------------
// One segment per block, 2 waves (128 thr). Wave w owns feat/fout half 64w..64w+63.
// Single 10.25 KB LDS buffer role-switched: xt (feat-major [128][40]) <-> zb ([32][128] XOR-swz).
// launch_bounds (128,4): VGPR budget 128 >= demand ~110 -> NO scratch spill (R10: (128,6)
// capped at 85 and spilled xr wholesale -> 64 MB scratch writes, the whole kernel cost).
__global__ void __launch_bounds__(128, 4) k_gcn6(
    const float* __restrict__ x,
    const int* __restrict__ segstart, const int* __restrict__ segcnt,
    const unsigned* __restrict__ Abits,
    const short* __restrict__ Wt1, const float* __restrict__ b1,
    const short* __restrict__ Wt2, const float* __restrict__ b2,
    float* __restrict__ pooled)
{
    __shared__ short xt[128 * 40];
    __shared__ float dv[32];
    short* zb = xt;

    const int seg = blockIdx.x;
    const int t  = threadIdx.x;
    const int wv = t >> 6;
    const int l  = t & 63;
    const int fr = l & 15;
    const int g  = l >> 4;
    const int swz = (fr & 7) << 3;

    const int start = segstart[seg];
    const int cnt   = segcnt[seg];

    // ---- 1. issue X loads into registers (HBM latency hides under A-extract)
    const int f0 = (t & 15) * 8;       // 8 feats
    const int c0 = (t >> 4) * 4;       // 4 cols
    float xr[4][8];
    #pragma unroll
    for (int i = 0; i < 4; ++i) {
        if (c0 + i < cnt) {
            const float4* rp = (const float4*)(x + (size_t)(start + c0 + i) * NF + f0);
            float4 a = rp[0], b = rp[1];
            xr[i][0]=a.x; xr[i][1]=a.y; xr[i][2]=a.z; xr[i][3]=a.w;
            xr[i][4]=b.x; xr[i][5]=b.y; xr[i][6]=b.z; xr[i][7]=b.w;
        } else {
            #pragma unroll
            for (int j = 0; j < 8; ++j) xr[i][j] = 0.f;
        }
    }

    // ---- 2. A counts from nibble bitmap: lane covers rows fr & 16+fr, cols g*8..g*8+7
    const unsigned* ab = Abits + (size_t)seg * 128;
    const unsigned wd0 = ab[fr * 4 + g];
    const unsigned wd1 = ab[(16 + fr) * 4 + g];

    int s0 = 0, s1 = 0;
    #pragma unroll
    for (int j = 0; j < 8; ++j) {
        s0 += (int)((wd0 >> (4 * j)) & 15u);
        s1 += (int)((wd1 >> (4 * j)) & 15u);
    }
    s0 += __shfl_xor(s0, 16); s0 += __shfl_xor(s0, 32);   // row sums over col groups
    s1 += __shfl_xor(s1, 16); s1 += __shfl_xor(s1, 32);
    float dv0 = rsqrtf(1.0f + (float)s0);
    float dv1 = rsqrtf(1.0f + (float)s1);
    if (t < 16) { dv[t] = dv0; dv[16 + t] = dv1; }

    // ---- 3. store X transposed into xt (bf16 feat-major, stride 40)
    #pragma unroll
    for (int j = 0; j < 8; ++j) {
        uint2 w;
        w.x = pk2(xr[0][j], xr[1][j]);
        w.y = pk2(xr[2][j], xr[3][j]);
        *reinterpret_cast<uint2*>(&xt[(f0 + j) * 40 + c0]) = w;
    }
    __syncthreads();

    // ---- 4. finalize A into register B-fragments (rows fr, 16+fr; cols g*8..+7)
    bf16x8 bfr0, bfr1;
    {
        float dr0 = dv[fr];
        float dr1 = dv[16 + fr];
        float e0[8], e1[8];
        #pragma unroll
        for (int j = 0; j < 8; ++j) {
            int c = g * 8 + j;
            float dc = dv[c];
            float v0 = (float)((wd0 >> (4 * j)) & 15u) * dr0 * dc;
            float v1 = (float)((wd1 >> (4 * j)) & 15u) * dr1 * dc;
            if (c == fr)      v0 += dr0 * dr0;
            if (c == 16 + fr) v1 += dr1 * dr1;
            e0[j] = v0; e1[j] = v1;
        }
        U8 u0, u1;
        u0.u[0] = pk2(e0[0], e0[1]); u0.u[1] = pk2(e0[2], e0[3]);
        u0.u[2] = pk2(e0[4], e0[5]); u0.u[3] = pk2(e0[6], e0[7]);
        u1.u[0] = pk2(e1[0], e1[1]); u1.u[1] = pk2(e1[2], e1[3]);
        u1.u[2] = pk2(e1[4], e1[5]); u1.u[3] = pk2(e1[6], e1[7]);
        bfr0 = u0.v; bfr1 = u1.v;
    }

    // ---- 5. two GCN layers (wave w owns feat half 64w..64w+63)
    for (int layer = 0; layer < 2; ++layer) {
        const short* Wt = layer ? Wt2 : Wt1;
        const float* bb = layer ? b2  : b1;

        // Z-phase: wave w computes mt = 4w..4w+3 into registers
        unsigned zp[4][4];
        __builtin_amdgcn_s_setprio(1);
        #pragma unroll
        for (int mi = 0; mi < 4; ++mi) {
            int mt = wv * 4 + mi;
            bf16x8 af = *(const bf16x8*)&xt[(mt * 16 + fr) * 40 + g * 8];
            f32x4 z0 = {0.f, 0.f, 0.f, 0.f};
            f32x4 z1 = {0.f, 0.f, 0.f, 0.f};
            z0 = __builtin_amdgcn_mfma_f32_16x16x32_bf16(af, bfr0, z0, 0, 0, 0);
            z1 = __builtin_amdgcn_mfma_f32_16x16x32_bf16(af, bfr1, z1, 0, 0, 0);
            zp[mi][0] = pk2(z0[0], z0[1]); zp[mi][1] = pk2(z0[2], z0[3]);
            zp[mi][2] = pk2(z1[0], z1[1]); zp[mi][3] = pk2(z1[2], z1[3]);
        }
        __builtin_amdgcn_s_setprio(0);
        __syncthreads();    // all xt reads retired; buffer becomes zb

        #pragma unroll
        for (int mi = 0; mi < 4; ++mi) {
            int fb = (wv * 4 + mi) * 16 + 4 * g;
            uint2 w0, w1;
            w0.x = zp[mi][0]; w0.y = zp[mi][1];
            w1.x = zp[mi][2]; w1.y = zp[mi][3];
            *reinterpret_cast<uint2*>(&zb[fr * 128 + (fb ^ swz)])        = w0;
            *reinterpret_cast<uint2*>(&zb[(16 + fr) * 128 + (fb ^ swz)]) = w1;
        }
        __syncthreads();

        // H-phase: wave w computes nt = 4w..4w+3 (fouts 64w..64w+63), K = all 128
        f32x4 acc[2][4];
        #pragma unroll
        for (int i = 0; i < 2; ++i)
            #pragma unroll
            for (int j = 0; j < 4; ++j) acc[i][j] = (f32x4){0.f, 0.f, 0.f, 0.f};
        #pragma unroll
        for (int kk = 0; kk < 4; ++kk) {
            const int ko = kk * 32 + g * 8;
            bf16x8 a0 = *(const bf16x8*)&zb[fr * 128 + (ko ^ swz)];
            bf16x8 a1 = *(const bf16x8*)&zb[(16 + fr) * 128 + (ko ^ swz)];
            __builtin_amdgcn_s_setprio(1);
            #pragma unroll
            for (int ni = 0; ni < 4; ++ni) {
                int nt = wv * 4 + ni;
                bf16x8 wf = *(const bf16x8*)&Wt[(nt * 16 + fr) * 128 + ko];
                acc[0][ni] = __builtin_amdgcn_mfma_f32_16x16x32_bf16(a0, wf, acc[0][ni], 0, 0, 0);
                acc[1][ni] = __builtin_amdgcn_mfma_f32_16x16x32_bf16(a1, wf, acc[1][ni], 0, 0, 0);
            }
            __builtin_amdgcn_s_setprio(0);
        }
        __syncthreads();    // zb reads retired (both waves)

        if (layer == 0) {
            #pragma unroll
            for (int ni = 0; ni < 4; ++ni) {
                int nt = wv * 4 + ni;
                float bv = bb[nt * 16 + fr];
                #pragma unroll
                for (int mt = 0; mt < 2; ++mt) {
                    float h0 = acc[mt][ni][0] + bv; h0 = h0 > 0.f ? h0 : 0.f;
                    float h1 = acc[mt][ni][1] + bv; h1 = h1 > 0.f ? h1 : 0.f;
                    float h2 = acc[mt][ni][2] + bv; h2 = h2 > 0.f ? h2 : 0.f;
                    float h3 = acc[mt][ni][3] + bv; h3 = h3 > 0.f ? h3 : 0.f;
                    uint2 w;
                    w.x = pk2(h0, h1); w.y = pk2(h2, h3);
                    *reinterpret_cast<uint2*>(&xt[(nt * 16 + fr) * 40 + mt * 16 + 4 * g]) = w;
                }
            }
            __syncthreads();
        } else {
            // mean pool in registers + shfl; wave w writes fouts 64w..64w+63
            float rcpc = 1.0f / (float)(cnt > 0 ? cnt : 1);
            #pragma unroll
            for (int ni = 0; ni < 4; ++ni) {
                int nt = wv * 4 + ni;
                float bv = bb[nt * 16 + fr];
                float pm = 0.f;
                #pragma unroll
                for (int mt = 0; mt < 2; ++mt)
                    #pragma unroll
                    for (int r = 0; r < 4; ++r) {
                        int node = mt * 16 + 4 * g + r;
                        float h = acc[mt][ni][r] + bv;
                        h = h > 0.f ? h : 0.f;
                        if (node < cnt) pm += h;
                    }
                pm += __shfl_xor(pm, 16);
                pm += __shfl_xor(pm, 32);
                if (l < 16) pooled[(size_t)seg * NF + nt * 16 + l] = pm * rcpc;
            }
        }
    }
}

// ---------------- K_mlp: pair MLP + sigmoid, 2 pairs per block, 256 threads ----------------
// 1024 blocks x 4 waves = 4096 waves (16/CU) vs R10's 1024 (4/CU): latency-hiding fix.
__global__ void __launch_bounds__(256) k_mlp(
    const float* __restrict__ pooled, const float* __restrict__ Wm1,
    const float* __restrict__ bm1, const float* __restrict__ Wm2,
    const float* __restrict__ bm2, float* __restrict__ out, int nB) {
    __shared__ float pr[2][256];
    __shared__ float red[2][2];
    const int b0 = blockIdx.x * 2;
    const int t = threadIdx.x;

    for (int i = t; i < 512; i += 256) {
        int p = i >> 8, c = i & 255;
        int pair = b0 + p;
        pr[p][c] = (pair < nB) ? pooled[(size_t)(2 * pair + (c >> 7)) * 128 + (c & 127)] : 0.f;
    }
    __syncthreads();

    const int p   = t >> 7;      // pair within block
    const int col = t & 127;
    float acc = bm1[col];
    #pragma unroll 8
    for (int k = 0; k < 256; ++k) acc += pr[p][k] * Wm1[k * 128 + col];
    float v = (acc > 0.f ? acc : 0.f) * Wm2[col];
    #pragma unroll
    for (int o = 32; o > 0; o >>= 1) v += __shfl_xor(v, o);
    if ((t & 63) == 0) red[t >> 7][(t >> 6) & 1] = v;   // wave 2p+h -> red[p][h]
    __syncthreads();
    if (t < 2 && b0 + t < nB) {
        float z = red[t][0] + red[t][1] + bm2[0];
        out[b0 + t] = 1.f / (1.f + expf(-z));
    }
}

static inline size_t alup(size_t v) { return (v + 255) & ~(size_t)255; }

extern "C" void kernel_launch(void* const* d_in, const int* in_sizes, int n_in,
                              void* d_out, int out_size, void* d_ws, size_t ws_size,
                              hipStream_t stream) {
    const float* x     = (const float*)d_in[0];
    const int*   edge  = (const int*)d_in[1];
    const int*   ptr   = (const int*)d_in[2];
    const int*   split = (const int*)d_in[3];
    const float* W1  = (const float*)d_in[4];
    const float* b1  = (const float*)d_in[5];
    const float* W2  = (const float*)d_in[6];
    const float* b2  = (const float*)d_in[7];
    const float* Wm1 = (const float*)d_in[8];
    const float* bm1 = (const float*)d_in[9];
    const float* Wm2 = (const float*)d_in[10];
    const float* bm2 = (const float*)d_in[11];
    float* out = (float*)d_out;

    const int N    = in_sizes[0] / NF;
    const int E    = in_sizes[1] / 2;
    const int nB   = in_sizes[2] - 1;
    const int nseg = 2 * nB;

    char* ws = (char*)d_ws;
    size_t off = 0;
    unsigned* segloc   = (unsigned*)(ws + off);  off += alup((size_t)N * 4);
    int*      segstart = (int*)(ws + off);       off += alup((size_t)nseg * 4);
    int*      segcnt   = (int*)(ws + off);       off += alup((size_t)nseg * 4);
    unsigned* Abits    = (unsigned*)(ws + off);  size_t abb = (size_t)nseg * 128 * 4; off += alup(abb);
    float*    pooled   = (float*)(ws + off);     off += alup((size_t)nseg * NF * 4);
    short*    Wt1      = (short*)(ws + off);     off += alup(128 * 128 * 2);
    short*    Wt2      = (short*)(ws + off);     off += alup(128 * 128 * 2);

    const int* srcp = edge;
    const int* dstp = edge + E;

    int prepN = N > 32768 ? N : 32768;
    if (prepN < nseg) prepN = nseg;

    hipMemsetAsync(Abits, 0, abb, stream);
    k_prep<<<(prepN + 255) / 256, 256, 0, stream>>>(ptr, split, nB, N, nseg,
                                                    segloc, segstart, segcnt,
                                                    W1, W2, Wt1, Wt2);
    k_cnt<<<(E + 255) / 256, 256, 0, stream>>>(srcp, dstp, E, segloc, Abits);
    k_gcn6<<<nseg, 128, 0, stream>>>(x, segstart, segcnt, Abits,
                                     Wt1, b1, Wt2, b2, pooled);
    k_mlp<<<(nB + 1) / 2, 256, 0, stream>>>(pooled, Wm1, bm1, Wm2, bm2, out, nB);
}